// Round 10
// baseline (173.046 us; speedup 1.0000x reference)
//
#include <hip/hip_runtime.h>
#include <hip/hip_bf16.h>

#define CC   128
#define HH_  64
#define WW_  64
#define BB   8
#define HWSZ (HH_*WW_)      // 4096
#define CHW  (CC*HWSZ)      // 524288
#define BCHW (BB*CHW)       // 4194304
#define PAD  3
#define NP   49

typedef __attribute__((ext_vector_type(8))) short short8;
typedef __attribute__((ext_vector_type(4))) float float4v;

__device__ __forceinline__ void split_bf16(float f, unsigned short& hu,
                                           unsigned short& lu) {
    __hip_bfloat16 h = __float2bfloat16(f);
    float hf = __bfloat162float(h);
    __hip_bfloat16 l = __float2bfloat16(f - hf);
    __builtin_memcpy(&hu, &h, 2);
    __builtin_memcpy(&lu, &l, 2);
}

// ============ Kernel 0: W -> bf16 hi/lo split ===============================
__global__ __launch_bounds__(256) void prep_w(
    const float* __restrict__ Wq, const float* __restrict__ Wk,
    const float* __restrict__ Wv,
    unsigned short* __restrict__ whi, unsigned short* __restrict__ wlo)
{
    int i = blockIdx.x * 256 + threadIdx.x;          // 0..49151
    const float* src = (i < 16384) ? Wq : (i < 32768 ? Wk : Wv);
    float f = src[i & 16383];
    split_bf16(f, whi[i], wlo[i]);
}

// ============ Kernel 1: q/k/v GEMM — split-bf16 MFMA, 32-px tiles ===========
// Grid (128 px-tiles, 8 b) = 1024 blocks (~4/CU, 16 waves/CU). 256 thr =
// 4 waves; wm = out-half (64 rows), wn = px-half (16 px). Block tile
// 128 out x 32 px, proj-looped (x converted ONCE). LDS 17.4 KB.
__global__ __launch_bounds__(256) void qkv_mfma(
    const float* __restrict__ x,
    const unsigned short* __restrict__ whi, const unsigned short* __restrict__ wlo,
    const float* __restrict__ bq, const float* __restrict__ bk,
    const float* __restrict__ bv, float* __restrict__ qkv)
{
    __shared__ __align__(16) unsigned short sh[32][136];   // [px][c] hi
    __shared__ __align__(16) unsigned short sl[32][136];   // [px][c] lo
    const int px0  = blockIdx.x << 5;
    const int b    = blockIdx.y;
    const int tid  = threadIdx.x;
    const int lane = tid & 63;
    const int wv   = tid >> 6;
    const int wm   = wv & 1, wn = wv >> 1;
    const int row16 = lane & 15;
    const int q4    = lane >> 4;
    const int kq8   = q4 << 3;

    // ---- stage + convert + transpose x tile: 128 c x 32 px ----
    const float* xb = x + (size_t)b*CHW + px0;
    #pragma unroll
    for (int it = 0; it < 4; ++it) {
        int f   = tid + (it << 8);      // 0..1023 = 128c x 8 quads
        int c   = f >> 3;
        int p4  = (f & 7) << 2;
        float4 v = *(const float4*)&xb[(size_t)c*HWSZ + p4];
        float vv[4] = {v.x, v.y, v.z, v.w};
        #pragma unroll
        for (int u = 0; u < 4; ++u)
            split_bf16(vv[u], sh[p4 + u][c], sl[p4 + u][c]);
    }
    __syncthreads();

    const int n = (wn << 4) + row16;   // px col 0..31

    for (int proj = 0; proj < 3; ++proj) {
        const float* Bp = (proj == 0) ? bq : (proj == 1 ? bk : bv);
        float4v acc[4];
        #pragma unroll
        for (int sm = 0; sm < 4; ++sm) {
            const int mb = wm*64 + sm*16 + q4*4;
            float4v bi;
            bi[0] = Bp[mb+0]; bi[1] = Bp[mb+1]; bi[2] = Bp[mb+2]; bi[3] = Bp[mb+3];
            acc[sm] = bi;
        }

        const unsigned short* Wh = whi + (size_t)proj*16384;
        const unsigned short* Wl = wlo + (size_t)proj*16384;

        #pragma unroll
        for (int pass = 0; pass < 3; ++pass) {
            const unsigned short* Wp = (pass == 2) ? Wl : Wh;
            const unsigned short (*Xp)[136] = (pass == 1) ? sl : sh;
            // preload all A-frags for this pass (16 b128 VMEM in flight)
            short8 a[4][4];
            #pragma unroll
            for (int kc = 0; kc < 4; ++kc)
                #pragma unroll
                for (int sm = 0; sm < 4; ++sm) {
                    const int m = wm*64 + sm*16 + row16;
                    a[kc][sm] = *(const short8*)&Wp[(size_t)m*CC + (kc<<5) + kq8];
                }
            #pragma unroll
            for (int kc = 0; kc < 4; ++kc) {
                short8 bb = *(const short8*)&Xp[n][(kc<<5) + kq8];
                #pragma unroll
                for (int sm = 0; sm < 4; ++sm)
                    acc[sm] = __builtin_amdgcn_mfma_f32_16x16x32_bf16(
                        a[kc][sm], bb, acc[sm], 0, 0, 0);
            }
        }

        float* op = qkv + (size_t)proj*BCHW + (size_t)b*CHW + px0;
        #pragma unroll
        for (int sm = 0; sm < 4; ++sm) {
            const int mb = wm*64 + sm*16 + q4*4;
            #pragma unroll
            for (int r = 0; r < 4; ++r)
                op[(size_t)(mb + r)*HWSZ + n] = acc[sm][r];
        }
    }
}

// ================= Kernel 2: local attention v5 (reverted, verified) ========
// Block = (b, h0..h0+1), 512 thr (8 waves). k/v read straight from global with
// 3x b128 contiguous window [w4-4, w4+8). Only LDS: logits lg + softmax.
// Phase C r-loop NOT unrolled (no spill).
__device__ __forceinline__ void win12(const float* __restrict__ rowp,
                                      bool rv, int q16, float* kw) {
    float4 a, b, c;
    if (rv) {
        a = *(const float4*)(rowp - 4);   // cols w4-4 .. w4-1
        b = *(const float4*)(rowp);       // cols w4   .. w4+3
        c = *(const float4*)(rowp + 4);   // cols w4+4 .. w4+7
        if (q16 == 0)  { a.x = a.y = a.z = a.w = 0.f; }   // cols <0
        if (q16 == 15) { c.x = c.y = c.z = c.w = 0.f; }   // cols >=64
    } else {
        a = b = c = make_float4(0.f, 0.f, 0.f, 0.f);
    }
    kw[0]=a.x; kw[1]=a.y; kw[2]=a.z;  kw[3]=a.w;
    kw[4]=b.x; kw[5]=b.y; kw[6]=b.z;  kw[7]=b.w;
    kw[8]=c.x; kw[9]=c.y; kw[10]=c.z; kw[11]=c.w;
}

__global__ __launch_bounds__(512) void locatt(
    const float* __restrict__ qkv, float* __restrict__ out)
{
    __shared__ float lg[2][NP][64];   // 25088 B
    __shared__ float dn[2][64];

    const int blk = blockIdx.x;
    const int xsw = blk & 7;
    const int jj  = blk >> 3;
    const int b   = jj >> 2;
    const int h0  = (((xsw << 2) | (jj & 3)) << 1);   // 2-row tile origin
    const int tid  = threadIdx.x;
    const int s    = tid >> 6;     // wave 0..7
    const int lane = tid & 63;
    const int q16  = lane & 15;
    const int csub = lane >> 4;
    const int w4   = q16 << 2;

    const float* qp = qkv + (size_t)b*CHW;
    const float* kp = qkv + (size_t)BCHW + (size_t)b*CHW;
    const float* vp = qkv + (size_t)2*BCHW + (size_t)b*CHW;

    const bool do0 = (s < 7);
    const bool do1 = (s >= 1);
    const int  hhk = h0 - PAD + s;
    const bool kv_ok = (unsigned)hhk < (unsigned)HH_;

    float acc0[7][4], acc1[7][4];
    #pragma unroll
    for (int dx = 0; dx < 7; ++dx)
        #pragma unroll
        for (int j = 0; j < 4; ++j) { acc0[dx][j] = 0.f; acc1[dx][j] = 0.f; }

    // -------- Phase A: logits (no LDS, no barriers) --------
    for (int ck = 0; ck < 8; ++ck) {
        const int c0 = ck << 4;
        #pragma unroll
        for (int ci4 = 0; ci4 < 4; ++ci4) {
            const int c = c0 + (ci4 << 2) + csub;
            float kw[12];
            win12(kp + (size_t)c*HWSZ + (long)hhk*WW_ + w4, kv_ok, q16, kw);
            const float* qc = qp + (size_t)c*HWSZ + h0*WW_ + w4;
            float4 q0v = do0 ? *(const float4*)qc
                             : make_float4(0.f, 0.f, 0.f, 0.f);
            float4 q1v = do1 ? *(const float4*)(qc + WW_)
                             : make_float4(0.f, 0.f, 0.f, 0.f);
            float q0a[4] = {q0v.x, q0v.y, q0v.z, q0v.w};
            float q1a[4] = {q1v.x, q1v.y, q1v.z, q1v.w};
            #pragma unroll
            for (int dx = 0; dx < 7; ++dx)
                #pragma unroll
                for (int j = 0; j < 4; ++j) {
                    float kvv = kw[j + dx + 1];   // col w4+j+dx-3
                    acc0[dx][j] = fmaf(q0a[j], kvv, acc0[dx][j]);
                    acc1[dx][j] = fmaf(q1a[j], kvv, acc1[dx][j]);
                }
        }
    }

    #pragma unroll
    for (int dx = 0; dx < 7; ++dx)
        #pragma unroll
        for (int j = 0; j < 4; ++j) {
            acc0[dx][j] += __shfl_xor(acc0[dx][j], 16, 64);
            acc0[dx][j] += __shfl_xor(acc0[dx][j], 32, 64);
            acc1[dx][j] += __shfl_xor(acc1[dx][j], 16, 64);
            acc1[dx][j] += __shfl_xor(acc1[dx][j], 32, 64);
        }
    #pragma unroll
    for (int dx = 0; dx < 7; ++dx) {
        if ((dx & 3) == csub) {
            if (do0) *(float4*)&lg[0][s*7 + dx][w4] =
                make_float4(acc0[dx][0], acc0[dx][1], acc0[dx][2], acc0[dx][3]);
            if (do1) *(float4*)&lg[1][(s-1)*7 + dx][w4] =
                make_float4(acc1[dx][0], acc1[dx][1], acc1[dx][2], acc1[dx][3]);
        }
    }
    __syncthreads();

    // -------- Phase B: two softmaxes (OOB logits exactly 0, included) ------
    if (tid < 128) {
        const int r = tid >> 6, px = tid & 63;
        float tv[NP];
        float m = -1e30f;
        #pragma unroll
        for (int p = 0; p < NP; ++p) { tv[p] = lg[r][p][px]; m = fmaxf(m, tv[p]); }
        float d = 0.f;
        #pragma unroll
        for (int p = 0; p < NP; ++p) {
            float e = __expf(tv[p] - m);
            d += e;
            lg[r][p][px] = e;
        }
        dn[r][px] = 1.f / d;
    }
    __syncthreads();

    // -------- Phase C: y = attn . v  (r-loop NOT unrolled: no spill) -------
    float y0[4][4], y1[4][4];
    #pragma unroll
    for (int cg = 0; cg < 4; ++cg)
        #pragma unroll
        for (int j = 0; j < 4; ++j) { y0[cg][j] = 0.f; y1[cg][j] = 0.f; }

    const int cbase = (s << 2) + csub;
    #pragma unroll 1
    for (int r = 0; r < 8; ++r) {
        const int hh = h0 - PAD + r;
        const bool rv = (unsigned)hh < (unsigned)HH_;
        float vw[4][12];
        #pragma unroll
        for (int cg = 0; cg < 4; ++cg) {
            const int c = (cg << 5) + cbase;
            win12(vp + (size_t)c*HWSZ + (long)hh*WW_ + w4, rv, q16, vw[cg]);
        }
        const bool r0 = (r < 7);    // wave-uniform
        const bool r1 = (r >= 1);
        #pragma unroll
        for (int dx = 0; dx < 7; ++dx) {
            if (r0) {
                float4 aq = *(const float4*)&lg[0][r*7 + dx][w4];
                float aa[4] = {aq.x, aq.y, aq.z, aq.w};
                #pragma unroll
                for (int cg = 0; cg < 4; ++cg)
                    #pragma unroll
                    for (int j = 0; j < 4; ++j)
                        y0[cg][j] = fmaf(aa[j], vw[cg][j + dx + 1], y0[cg][j]);
            }
            if (r1) {
                float4 aq = *(const float4*)&lg[1][(r-1)*7 + dx][w4];
                float aa[4] = {aq.x, aq.y, aq.z, aq.w};
                #pragma unroll
                for (int cg = 0; cg < 4; ++cg)
                    #pragma unroll
                    for (int j = 0; j < 4; ++j)
                        y1[cg][j] = fmaf(aa[j], vw[cg][j + dx + 1], y1[cg][j]);
            }
        }
    }

    const float4 s0v = *(const float4*)&dn[0][w4];
    const float4 s1v = *(const float4*)&dn[1][w4];
    const float s0a[4] = {s0v.x, s0v.y, s0v.z, s0v.w};
    const float s1a[4] = {s1v.x, s1v.y, s1v.z, s1v.w};
    #pragma unroll
    for (int cg = 0; cg < 4; ++cg) {
        const int c = (cg << 5) + cbase;
        float* op = out + (size_t)b*CHW + (size_t)c*HWSZ + (size_t)h0*WW_ + w4;
        float4 o0 = make_float4(y0[cg][0]*s0a[0], y0[cg][1]*s0a[1],
                                y0[cg][2]*s0a[2], y0[cg][3]*s0a[3]);
        float4 o1 = make_float4(y1[cg][0]*s1a[0], y1[cg][1]*s1a[1],
                                y1[cg][2]*s1a[2], y1[cg][3]*s1a[3]);
        *(float4*)op         = o0;
        *(float4*)(op + WW_) = o1;
    }
}

extern "C" void kernel_launch(void* const* d_in, const int* in_sizes, int n_in,
                              void* d_out, int out_size, void* d_ws, size_t ws_size,
                              hipStream_t stream) {
    const float* x  = (const float*)d_in[0];
    const float* Wq = (const float*)d_in[1];
    const float* bq = (const float*)d_in[2];
    const float* Wk = (const float*)d_in[3];
    const float* bk = (const float*)d_in[4];
    const float* Wv = (const float*)d_in[5];
    const float* bv = (const float*)d_in[6];
    float* out = (float*)d_out;

    // ws layout: qkv (50.3 MB) | whi,wlo (2x96 KB)
    float* qkv = (float*)d_ws;
    unsigned short* whi = (unsigned short*)(qkv + (size_t)3*BCHW);
    unsigned short* wlo = whi + 3*16384;

    prep_w  <<<192, 256, 0, stream>>>(Wq, Wk, Wv, whi, wlo);
    qkv_mfma<<<dim3(128, 8), 256, 0, stream>>>(x, whi, wlo, bq, bk, bv, qkv);
    locatt  <<<256, 512, 0, stream>>>(qkv, out);
}